// Round 1
// baseline (1271.973 us; speedup 1.0000x reference)
//
#include <hip/hip_runtime.h>
#include <hip/hip_bf16.h>

// Problem constants (B=1)
#define T_ 8
#define H_ 64
#define W_ 64
#define C_ 64
#define HW_ (H_ * W_)          // 4096
#define THW_ (T_ * H_ * W_)    // 32768
#define KTAPS 27

// ---------------------------------------------------------------------------
// prep: transpose Wd (cout,cin,k) -> WdT (k,cin,cout); Wr (cout,cin) -> WrT (cin,cout)
// ---------------------------------------------------------------------------
__global__ void prep_kernel(const float* __restrict__ wd, const float* __restrict__ wr,
                            float* __restrict__ wdT, float* __restrict__ wrT) {
    int i = blockIdx.x * 256 + threadIdx.x;
    if (i < C_ * C_ * KTAPS) {
        int k = i % KTAPS;
        int r = i / KTAPS;
        int cin = r % C_;
        int co = r / C_;
        wdT[(k * C_ + cin) * C_ + co] = wd[i];
    }
    if (i < C_ * C_) {
        int cin = i % C_;
        int co = i / C_;
        wrT[cin * C_ + co] = wr[i];
    }
}

// ---------------------------------------------------------------------------
// Generic 3x3x3 conv, pad=1, Cin=64, channel-first input.
//   out_cf : channel-first output (always)
//   out_cl : channel-last output (T,H,W,C) when WRITE_CL (for deform gather)
// Block: 256 threads = 16x16 spatial tile; blockIdx = (spatial 16, t 8, co-chunk)
// Each thread: 16 cout accumulators.
// ---------------------------------------------------------------------------
template <bool LRELU, bool WRITE_CL>
__global__ __launch_bounds__(256) void conv3x3x3_kernel(
    const float* __restrict__ x,    // (64, T, H, W)
    const float* __restrict__ wgt,  // (cout_n, 64, 27)
    const float* __restrict__ bias, // (cout_n)
    float* __restrict__ out_cf,     // (cout_n, T, H, W)
    float* __restrict__ out_cl,     // (T, H, W, 64) or unused
    int cout_n) {
    __shared__ float xs[8][3][18][18];               // 31104 B
    __shared__ float ts[WRITE_CL ? 256 * 17 : 1];    // 17408 B when used (pad 17 kills conflicts)

    const int tid = threadIdx.x;
    const int tx = tid & 15, ty = tid >> 4;
    const int bw = blockIdx.x & 3, bh = blockIdx.x >> 2;
    const int t = blockIdx.y;
    const int co0 = blockIdx.z * 16;
    const int h0 = bh * 16, w0 = bw * 16;
    const int h = h0 + ty, w = w0 + tx;

    float acc[16];
#pragma unroll
    for (int co = 0; co < 16; ++co) acc[co] = bias[min(co0 + co, cout_n - 1)];

    for (int cc = 0; cc < 8; ++cc) {  // cin chunks of 8
        // stage slab: cins [cc*8, cc*8+8), t-1..t+1, 18x18 halo, zero-padded
        for (int i = tid; i < 8 * 3 * 18 * 18; i += 256) {
            int ww = i % 18;
            int r = i / 18;
            int hh = r % 18; r /= 18;
            int kt = r % 3;
            int ci = r / 3;
            int gt = t - 1 + kt;
            int gh = h0 - 1 + hh;
            int gw = w0 - 1 + ww;
            float v = 0.f;
            if ((unsigned)gt < T_ && (unsigned)gh < H_ && (unsigned)gw < W_)
                v = x[(cc * 8 + ci) * THW_ + gt * HW_ + gh * W_ + gw];
            xs[ci][kt][hh][ww] = v;
        }
        __syncthreads();

        for (int ci = 0; ci < 8; ++ci) {
            float xv[27];
#pragma unroll
            for (int kt = 0; kt < 3; ++kt)
#pragma unroll
                for (int kh = 0; kh < 3; ++kh)
#pragma unroll
                    for (int kw = 0; kw < 3; ++kw)
                        xv[kt * 9 + kh * 3 + kw] = xs[ci][kt][ty + kh][tx + kw];
            const int cin = cc * 8 + ci;
#pragma unroll
            for (int co = 0; co < 16; ++co) {
                const int coc = min(co0 + co, cout_n - 1);
                const float* wp = wgt + (coc * C_ + cin) * KTAPS;
#pragma unroll
                for (int k = 0; k < KTAPS; ++k) acc[co] = fmaf(wp[k], xv[k], acc[co]);
            }
        }
        __syncthreads();
    }

    const int pos = t * HW_ + h * W_ + w;
#pragma unroll
    for (int co = 0; co < 16; ++co) {
        float v = acc[co];
        if (LRELU) v = (v >= 0.f) ? v : 0.01f * v;
        if (co0 + co < cout_n) out_cf[(co0 + co) * THW_ + pos] = v;
        if constexpr (WRITE_CL) ts[tid * 17 + co] = v;
    }
    if constexpr (WRITE_CL) {
        __syncthreads();
        // cooperative channel-last write: 16 contiguous floats (64B) per position
        for (int i = tid; i < 256 * 16; i += 256) {
            int co = i & 15;
            int p = i >> 4;
            int ph = p >> 4, pw = p & 15;
            out_cl[((t * H_ + h0 + ph) * W_ + (w0 + pw)) * C_ + co0 + co] = ts[p * 17 + co];
        }
    }
}

// ---------------------------------------------------------------------------
// Deformable conv (H/W bilinear, T integral) + bias + lrelu + 1x1 residual.
// y1cl: (T,H,W,64) channel-last. off: (54,T,H,W) channel-first.
// wdT: (27,64cin,64cout). out: (64,T,H,W).
// ---------------------------------------------------------------------------
__global__ __launch_bounds__(256) void deform_kernel(
    const float* __restrict__ y1cl, const float* __restrict__ off,
    const float* __restrict__ wdT, const float* __restrict__ bd,
    const float* __restrict__ x, const float* __restrict__ wrT,
    const float* __restrict__ br, float* __restrict__ out) {
    const int tid = threadIdx.x;
    const int tx = tid & 15, ty = tid >> 4;
    const int bw = blockIdx.x & 3, bh = blockIdx.x >> 2;
    const int t = blockIdx.y;
    const int co0 = blockIdx.z * 16;
    const int h = bh * 16 + ty, w = bw * 16 + tx;
    const int pos = t * HW_ + h * W_ + w;

    float acc[16];
#pragma unroll
    for (int co = 0; co < 16; ++co) acc[co] = bd[co0 + co];

#pragma unroll 1
    for (int k = 0; k < KTAPS; ++k) {
        const int kt = k / 9, kh = (k / 3) % 3, kw = k % 3;
        const int t_in = t - 1 + kt;
        if ((unsigned)t_in >= T_) continue;  // block-uniform: no divergence

        const float dh = off[(2 * k) * THW_ + pos];
        const float dw = off[(2 * k + 1) * THW_ + pos];
        const float hs = (float)(h - 1 + kh) + dh;
        const float wsv = (float)(w - 1 + kw) + dw;
        const float h0f = floorf(hs), w0f = floorf(wsv);
        const float fh = hs - h0f, fw = wsv - w0f;
        const int h0i = (int)h0f, w0i = (int)w0f;
        const int h1i = h0i + 1, w1i = w0i + 1;
        const float m_h0 = ((unsigned)h0i < H_) ? 1.f : 0.f;
        const float m_h1 = ((unsigned)h1i < H_) ? 1.f : 0.f;
        const float m_w0 = ((unsigned)w0i < W_) ? 1.f : 0.f;
        const float m_w1 = ((unsigned)w1i < W_) ? 1.f : 0.f;
        const float w00 = (1.f - fh) * (1.f - fw) * m_h0 * m_w0;
        const float w01 = (1.f - fh) * fw * m_h0 * m_w1;
        const float w10 = fh * (1.f - fw) * m_h1 * m_w0;
        const float w11 = fh * fw * m_h1 * m_w1;
        const int h0c = min(max(h0i, 0), H_ - 1);
        const int h1c = min(max(h1i, 0), H_ - 1);
        const int w0c = min(max(w0i, 0), W_ - 1);
        const int w1c = min(max(w1i, 0), W_ - 1);

        const float* p00 = y1cl + ((t_in * H_ + h0c) * W_ + w0c) * C_;
        const float* p01 = y1cl + ((t_in * H_ + h0c) * W_ + w1c) * C_;
        const float* p10 = y1cl + ((t_in * H_ + h1c) * W_ + w0c) * C_;
        const float* p11 = y1cl + ((t_in * H_ + h1c) * W_ + w1c) * C_;
        const float* wk = wdT + k * C_ * C_ + co0;  // [cin][cout] slice, lane-uniform

#pragma unroll 4
        for (int cg = 0; cg < 16; ++cg) {  // 4 cins per group
            const float4 v00 = *(const float4*)(p00 + cg * 4);
            const float4 v01 = *(const float4*)(p01 + cg * 4);
            const float4 v10 = *(const float4*)(p10 + cg * 4);
            const float4 v11 = *(const float4*)(p11 + cg * 4);
            float4 col;
            col.x = w00 * v00.x + w01 * v01.x + w10 * v10.x + w11 * v11.x;
            col.y = w00 * v00.y + w01 * v01.y + w10 * v10.y + w11 * v11.y;
            col.z = w00 * v00.z + w01 * v01.z + w10 * v10.z + w11 * v11.z;
            col.w = w00 * v00.w + w01 * v01.w + w10 * v10.w + w11 * v11.w;
#pragma unroll
            for (int co = 0; co < 16; ++co) {
                acc[co] = fmaf(wk[(cg * 4 + 0) * C_ + co], col.x, acc[co]);
                acc[co] = fmaf(wk[(cg * 4 + 1) * C_ + co], col.y, acc[co]);
                acc[co] = fmaf(wk[(cg * 4 + 2) * C_ + co], col.z, acc[co]);
                acc[co] = fmaf(wk[(cg * 4 + 3) * C_ + co], col.w, acc[co]);
            }
        }
    }

    // residual: 1x1 conv on x, fused
    float racc[16];
#pragma unroll
    for (int co = 0; co < 16; ++co) racc[co] = br[co0 + co];
    for (int cin = 0; cin < C_; ++cin) {
        const float xv = x[cin * THW_ + pos];
        const float* wr = wrT + cin * C_ + co0;
#pragma unroll
        for (int co = 0; co < 16; ++co) racc[co] = fmaf(wr[co], xv, racc[co]);
    }

#pragma unroll
    for (int co = 0; co < 16; ++co) {
        float v = acc[co];
        v = (v >= 0.f) ? v : 0.01f * v;
        out[(co0 + co) * THW_ + pos] = v + racc[co];
    }
}

// ---------------------------------------------------------------------------
extern "C" void kernel_launch(void* const* d_in, const int* in_sizes, int n_in,
                              void* d_out, int out_size, void* d_ws, size_t ws_size,
                              hipStream_t stream) {
    const float* x    = (const float*)d_in[0];
    const float* W1   = (const float*)d_in[1];
    const float* b1   = (const float*)d_in[2];
    const float* Woff = (const float*)d_in[3];
    const float* boff = (const float*)d_in[4];
    const float* Wd   = (const float*)d_in[5];
    const float* bd   = (const float*)d_in[6];
    const float* Wr   = (const float*)d_in[7];
    const float* br   = (const float*)d_in[8];
    float* out = (float*)d_out;

    float* ws = (float*)d_ws;
    float* y1cf  = ws;                       // 2,097,152 f
    float* y1cl  = ws + 2097152;             // 2,097,152 f
    float* offcf = ws + 4194304;             // 1,769,472 f
    float* wdT   = ws + 5963776;             //   110,592 f
    float* wrT   = ws + 6074368;             //     4,096 f  (total ~24.3 MB)

    prep_kernel<<<(C_ * C_ * KTAPS + 255) / 256, 256, 0, stream>>>(Wd, Wr, wdT, wrT);

    // y1 = lrelu(conv(x, W1, b1)), both layouts
    conv3x3x3_kernel<true, true><<<dim3(16, T_, 4), 256, 0, stream>>>(
        x, W1, b1, y1cf, y1cl, 64);

    // offsets = conv(y1, W_off, b_off), channel-first
    conv3x3x3_kernel<false, false><<<dim3(16, T_, 4), 256, 0, stream>>>(
        y1cf, Woff, boff, offcf, nullptr, 54);

    // y2 = lrelu(deform(y1, offsets, Wd, bd)) + (Wr·x + br)
    deform_kernel<<<dim3(16, T_, 4), 256, 0, stream>>>(
        y1cl, offcf, wdT, bd, x, wrT, br, out);
}

// Round 2
// 567.286 us; speedup vs baseline: 2.2422x; 2.2422x over previous
//
#include <hip/hip_runtime.h>
#include <hip/hip_bf16.h>

// Problem constants (B=1)
#define T_ 8
#define H_ 64
#define W_ 64
#define C_ 64
#define HW_ (H_ * W_)          // 4096
#define THW_ (T_ * H_ * W_)    // 32768
#define KTAPS 27
#define KDIM (C_ * KTAPS)      // 1728
#define NOFF 54

typedef __bf16 bf16x8 __attribute__((ext_vector_type(8)));
typedef float floatx4 __attribute__((ext_vector_type(4)));

// ---------------------------------------------------------------------------
// prep: weight transforms.
//  wT1b   (64, 1728) bf16 : wT1b[co][tap*64+cin]  = W1[co][cin][tap]
//  wToffb (64, 1728) bf16 : rows >= 54 zeroed
//  wdT    (27,64,64) fp32 : wdT[(k*64+cin)*64+co] = Wd[co][cin][k]   (deform)
//  wrT    (64,64)    fp32 : wrT[cin][co]          = Wr[co][cin]      (residual)
// ---------------------------------------------------------------------------
__global__ void prep_kernel(const float* __restrict__ w1, const float* __restrict__ woff,
                            const float* __restrict__ wd, const float* __restrict__ wr,
                            __hip_bfloat16* __restrict__ wT1b, __hip_bfloat16* __restrict__ wToffb,
                            float* __restrict__ wdT, float* __restrict__ wrT) {
    int i = blockIdx.x * 256 + threadIdx.x;
    if (i < C_ * KDIM) {
        int k = i % KDIM;          // k = tap*64 + cin
        int co = i / KDIM;
        int tap = k >> 6, cin = k & 63;
        wT1b[i] = __float2bfloat16(w1[(co * C_ + cin) * KTAPS + tap]);
        wToffb[i] = (co < NOFF) ? __float2bfloat16(woff[(co * C_ + cin) * KTAPS + tap])
                                : __float2bfloat16(0.f);
    }
    if (i < C_ * C_ * KTAPS) {
        int k = i % KTAPS;
        int r = i / KTAPS;
        int cin = r % C_;
        int co = r / C_;
        wdT[(k * C_ + cin) * C_ + co] = wd[i];
    }
    if (i < C_ * C_) {
        int cin = i % C_;
        int co = i / C_;
        wrT[cin * C_ + co] = wr[i];
    }
}

// ---------------------------------------------------------------------------
// x (64, T, H, W) fp32 channel-first -> x_cl (T,H,W,64) bf16 channel-last
// ---------------------------------------------------------------------------
__global__ void to_cl_kernel(const float* __restrict__ x, __hip_bfloat16* __restrict__ xcl) {
    int i = blockIdx.x * 256 + threadIdx.x;   // over 2,097,152
    int pos = i >> 6, ch = i & 63;
    xcl[i] = __float2bfloat16(x[ch * THW_ + pos]);
}

// ---------------------------------------------------------------------------
// MFMA implicit-GEMM 3x3x3 conv, pad=1.
//  in_cl : (T,H,W,64) bf16    wT : (64, 1728) bf16 [cout][tap*64+cin]
//  Block = 256 thr = 4 waves; block covers (t,h) fixed, w=0..63, all 64 couts.
//  Wave wv handles couts [wv*16, wv*16+16); 4 m-subtiles of 16 w-positions.
//  D = A(pos x K) * B(K x cout) via mfma_f32_16x16x32_bf16, 216 MFMA/wave.
//  CONV1 epilogue: +bias, lrelu, write channel-last fp32 + bf16 (LDS bounce).
//  else (offsets conv): +bias, write channel-first fp32, guard cout<NCO.
// ---------------------------------------------------------------------------
template <bool CONV1>
__global__ __launch_bounds__(256) void conv_mfma_kernel(
    const __hip_bfloat16* __restrict__ in_cl,
    const __hip_bfloat16* __restrict__ wT,
    const float* __restrict__ bias,
    float* __restrict__ out_cl_f32,          // CONV1: (T,H,W,64)
    __hip_bfloat16* __restrict__ out_cl_b16, // CONV1: (T,H,W,64)
    float* __restrict__ out_cf,              // !CONV1: (NCO,T,H,W)
    int nco) {
    __shared__ float ts[CONV1 ? 64 * 68 : 1];

    const int tid = threadIdx.x;
    const int wv = tid >> 6;
    const int lane = tid & 63;
    const int l15 = lane & 15;
    const int quad = lane >> 4;
    const int t = blockIdx.x >> 6;
    const int h = blockIdx.x & 63;
    const int n0 = wv * 16;
    const int n = n0 + l15;                  // this lane's cout (all regs)

    floatx4 acc[4];
#pragma unroll
    for (int m = 0; m < 4; ++m) acc[m] = (floatx4){0.f, 0.f, 0.f, 0.f};

    // lane-fixed pieces of addresses
    const __hip_bfloat16* wB = wT + n * KDIM + quad * 8;   // + tap*64 (+32 for s=1)
    const int wl = l15 - 1;                                 // w offset before +kw

    const bf16x8 zfrag = {};

#pragma unroll 1
    for (int kt = 0; kt < 3; ++kt) {
        const int t_in = t + kt - 1;
        if ((unsigned)t_in >= T_) continue;                 // uniform
#pragma unroll 1
        for (int kh = 0; kh < 3; ++kh) {
            const int h_in = h + kh - 1;
            if ((unsigned)h_in >= H_) continue;             // uniform
            const int rowbase = (t_in * HW_ + h_in * W_);
#pragma unroll
            for (int kw = 0; kw < 3; ++kw) {
                const int tap = kt * 9 + kh * 3 + kw;
                const bf16x8 b0 = *(const bf16x8*)(wB + tap * 64);
                const bf16x8 b1 = *(const bf16x8*)(wB + tap * 64 + 32);
#pragma unroll
                for (int m = 0; m < 4; ++m) {
                    const int w_in = m * 16 + wl + kw;
                    const bool v = (unsigned)w_in < W_;     // per-lane (edge subtiles)
                    const int wc = v ? w_in : 0;
                    const __hip_bfloat16* ap = in_cl + (rowbase + wc) * C_ + quad * 8;
                    bf16x8 a0 = *(const bf16x8*)(ap);
                    bf16x8 a1 = *(const bf16x8*)(ap + 32);
                    a0 = v ? a0 : zfrag;
                    a1 = v ? a1 : zfrag;
                    acc[m] = __builtin_amdgcn_mfma_f32_16x16x32_bf16(a0, b0, acc[m], 0, 0, 0);
                    acc[m] = __builtin_amdgcn_mfma_f32_16x16x32_bf16(a1, b1, acc[m], 0, 0, 0);
                }
            }
        }
    }

    const int posbase = t * HW_ + h * W_;   // linear (t,h,w=0) position

    if constexpr (CONV1) {
        const float bv = bias[n];
#pragma unroll
        for (int m = 0; m < 4; ++m)
#pragma unroll
            for (int r = 0; r < 4; ++r) {
                float v = acc[m][r] + bv;
                v = (v >= 0.f) ? v : 0.01f * v;             // lrelu
                ts[(m * 16 + quad * 4 + r) * 68 + n] = v;   // [w][cout], pad 68
            }
        __syncthreads();
        // cooperative coalesced channel-last stores (fp32 + bf16)
#pragma unroll
        for (int c = 0; c < 4; ++c) {
            const int flat4 = c * 256 + tid;                // 1024 float4 chunks
            const int w = flat4 >> 4, cg = flat4 & 15;
            const float4 v4 = *(const float4*)&ts[w * 68 + cg * 4];
            *(float4*)&out_cl_f32[(posbase + w) * C_ + cg * 4] = v4;
            __hip_bfloat16 hb[4] = {__float2bfloat16(v4.x), __float2bfloat16(v4.y),
                                    __float2bfloat16(v4.z), __float2bfloat16(v4.w)};
            *(uint2*)&out_cl_b16[(posbase + w) * C_ + cg * 4] = *(const uint2*)hb;
        }
    } else {
        const float bv = (n < nco) ? bias[n] : 0.f;
        if (n < nco) {
#pragma unroll
            for (int m = 0; m < 4; ++m) {
                floatx4 v = acc[m];
                v[0] += bv; v[1] += bv; v[2] += bv; v[3] += bv;
                // regs r=0..3 are consecutive w -> one 16B store
                *(floatx4*)&out_cf[n * THW_ + posbase + m * 16 + quad * 4] = v;
            }
        }
    }
}

// ---------------------------------------------------------------------------
// Deformable conv (H/W bilinear, T integral) + bias + lrelu + 1x1 residual.
// UNCHANGED from the passing R0 kernel.
// y1cl: (T,H,W,64) fp32 channel-last. off: (54,T,H,W) fp32 channel-first.
// wdT: (27,64cin,64cout). out: (64,T,H,W).
// ---------------------------------------------------------------------------
__global__ __launch_bounds__(256) void deform_kernel(
    const float* __restrict__ y1cl, const float* __restrict__ off,
    const float* __restrict__ wdT, const float* __restrict__ bd,
    const float* __restrict__ x, const float* __restrict__ wrT,
    const float* __restrict__ br, float* __restrict__ out) {
    const int tid = threadIdx.x;
    const int tx = tid & 15, ty = tid >> 4;
    const int bw = blockIdx.x & 3, bh = blockIdx.x >> 2;
    const int t = blockIdx.y;
    const int co0 = blockIdx.z * 16;
    const int h = bh * 16 + ty, w = bw * 16 + tx;
    const int pos = t * HW_ + h * W_ + w;

    float acc[16];
#pragma unroll
    for (int co = 0; co < 16; ++co) acc[co] = bd[co0 + co];

#pragma unroll 1
    for (int k = 0; k < KTAPS; ++k) {
        const int kt = k / 9, kh = (k / 3) % 3, kw = k % 3;
        const int t_in = t - 1 + kt;
        if ((unsigned)t_in >= T_) continue;  // block-uniform: no divergence

        const float dh = off[(2 * k) * THW_ + pos];
        const float dw = off[(2 * k + 1) * THW_ + pos];
        const float hs = (float)(h - 1 + kh) + dh;
        const float wsv = (float)(w - 1 + kw) + dw;
        const float h0f = floorf(hs), w0f = floorf(wsv);
        const float fh = hs - h0f, fw = wsv - w0f;
        const int h0i = (int)h0f, w0i = (int)w0f;
        const int h1i = h0i + 1, w1i = w0i + 1;
        const float m_h0 = ((unsigned)h0i < H_) ? 1.f : 0.f;
        const float m_h1 = ((unsigned)h1i < H_) ? 1.f : 0.f;
        const float m_w0 = ((unsigned)w0i < W_) ? 1.f : 0.f;
        const float m_w1 = ((unsigned)w1i < W_) ? 1.f : 0.f;
        const float w00 = (1.f - fh) * (1.f - fw) * m_h0 * m_w0;
        const float w01 = (1.f - fh) * fw * m_h0 * m_w1;
        const float w10 = fh * (1.f - fw) * m_h1 * m_w0;
        const float w11 = fh * fw * m_h1 * m_w1;
        const int h0c = min(max(h0i, 0), H_ - 1);
        const int h1c = min(max(h1i, 0), H_ - 1);
        const int w0c = min(max(w0i, 0), W_ - 1);
        const int w1c = min(max(w1i, 0), W_ - 1);

        const float* p00 = y1cl + ((t_in * H_ + h0c) * W_ + w0c) * C_;
        const float* p01 = y1cl + ((t_in * H_ + h0c) * W_ + w1c) * C_;
        const float* p10 = y1cl + ((t_in * H_ + h1c) * W_ + w0c) * C_;
        const float* p11 = y1cl + ((t_in * H_ + h1c) * W_ + w1c) * C_;
        const float* wk = wdT + k * C_ * C_ + co0;  // [cin][cout] slice, lane-uniform

#pragma unroll 4
        for (int cg = 0; cg < 16; ++cg) {  // 4 cins per group
            const float4 v00 = *(const float4*)(p00 + cg * 4);
            const float4 v01 = *(const float4*)(p01 + cg * 4);
            const float4 v10 = *(const float4*)(p10 + cg * 4);
            const float4 v11 = *(const float4*)(p11 + cg * 4);
            float4 col;
            col.x = w00 * v00.x + w01 * v01.x + w10 * v10.x + w11 * v11.x;
            col.y = w00 * v00.y + w01 * v01.y + w10 * v10.y + w11 * v11.y;
            col.z = w00 * v00.z + w01 * v01.z + w10 * v10.z + w11 * v11.z;
            col.w = w00 * v00.w + w01 * v01.w + w10 * v10.w + w11 * v11.w;
#pragma unroll
            for (int co = 0; co < 16; ++co) {
                acc[co] = fmaf(wk[(cg * 4 + 0) * C_ + co], col.x, acc[co]);
                acc[co] = fmaf(wk[(cg * 4 + 1) * C_ + co], col.y, acc[co]);
                acc[co] = fmaf(wk[(cg * 4 + 2) * C_ + co], col.z, acc[co]);
                acc[co] = fmaf(wk[(cg * 4 + 3) * C_ + co], col.w, acc[co]);
            }
        }
    }

    // residual: 1x1 conv on x, fused
    float racc[16];
#pragma unroll
    for (int co = 0; co < 16; ++co) racc[co] = br[co0 + co];
    for (int cin = 0; cin < C_; ++cin) {
        const float xv = x[cin * THW_ + pos];
        const float* wr = wrT + cin * C_ + co0;
#pragma unroll
        for (int co = 0; co < 16; ++co) racc[co] = fmaf(wr[co], xv, racc[co]);
    }

#pragma unroll
    for (int co = 0; co < 16; ++co) {
        float v = acc[co];
        v = (v >= 0.f) ? v : 0.01f * v;
        out[(co0 + co) * THW_ + pos] = v + racc[co];
    }
}

// ---------------------------------------------------------------------------
extern "C" void kernel_launch(void* const* d_in, const int* in_sizes, int n_in,
                              void* d_out, int out_size, void* d_ws, size_t ws_size,
                              hipStream_t stream) {
    const float* x    = (const float*)d_in[0];
    const float* W1   = (const float*)d_in[1];
    const float* b1   = (const float*)d_in[2];
    const float* Woff = (const float*)d_in[3];
    const float* boff = (const float*)d_in[4];
    const float* Wd   = (const float*)d_in[5];
    const float* bd   = (const float*)d_in[6];
    const float* Wr   = (const float*)d_in[7];
    const float* br   = (const float*)d_in[8];
    float* out = (float*)d_out;

    float* ws = (float*)d_ws;
    float* y1cl  = ws;                                   // 2,097,152 f  (T,H,W,64) fp32
    float* offcf = ws + 2097152;                         // 1,769,472 f  (54,T,H,W)
    float* wdT   = ws + 3866624;                         //   110,592 f
    float* wrT   = ws + 3977216;                         //     4,096 f
    __hip_bfloat16* xclb   = (__hip_bfloat16*)(ws + 3981312);  // 2,097,152 bf16
    __hip_bfloat16* y1b    = (__hip_bfloat16*)(ws + 5029888);  // 2,097,152 bf16
    __hip_bfloat16* wT1b   = (__hip_bfloat16*)(ws + 6078464);  //   110,592 bf16
    __hip_bfloat16* wToffb = (__hip_bfloat16*)(ws + 6133760);  //   110,592 bf16
    // total: 6,189,056 floats ~= 24.76 MB

    prep_kernel<<<(C_ * KDIM + 255) / 256, 256, 0, stream>>>(
        W1, Woff, Wd, Wr, wT1b, wToffb, wdT, wrT);

    to_cl_kernel<<<(C_ * THW_) / 256, 256, 0, stream>>>(x, xclb);

    // y1 = lrelu(conv(x, W1, b1)) -> channel-last fp32 + bf16
    conv_mfma_kernel<true><<<dim3(T_ * H_), 256, 0, stream>>>(
        xclb, wT1b, b1, y1cl, y1b, nullptr, 64);

    // offsets = conv(y1, W_off, b_off) -> channel-first fp32 (54 ch)
    conv_mfma_kernel<false><<<dim3(T_ * H_), 256, 0, stream>>>(
        y1b, wToffb, boff, nullptr, nullptr, offcf, NOFF);

    // y2 = lrelu(deform(y1, offsets, Wd, bd)) + (Wr·x + br)
    deform_kernel<<<dim3(16, T_, 4), 256, 0, stream>>>(
        y1cl, offcf, wdT, bd, x, wrT, br, out);
}

// Round 3
// 404.266 us; speedup vs baseline: 3.1464x; 1.4032x over previous
//
#include <hip/hip_runtime.h>
#include <hip/hip_bf16.h>

// Problem constants (B=1)
#define T_ 8
#define H_ 64
#define W_ 64
#define C_ 64
#define HW_ (H_ * W_)          // 4096
#define THW_ (T_ * H_ * W_)    // 32768
#define KTAPS 27
#define KDIM (C_ * KTAPS)      // 1728
#define NOFF 54

typedef __bf16 bf16x8 __attribute__((ext_vector_type(8)));
typedef float floatx4 __attribute__((ext_vector_type(4)));

// ---------------------------------------------------------------------------
// prep: weight transforms (all to bf16, B-fragment-friendly [cout][tap*64+cin])
//  wT1b   (64,1728) : W1      wToffb (64,1728) : W_off (rows>=54 zero)
//  wdTb   (64,1728) : Wd      wrTb   (64,64)   : Wr (already cin-contig)
// ---------------------------------------------------------------------------
__global__ void prep_kernel(const float* __restrict__ w1, const float* __restrict__ woff,
                            const float* __restrict__ wd, const float* __restrict__ wr,
                            __hip_bfloat16* __restrict__ wT1b, __hip_bfloat16* __restrict__ wToffb,
                            __hip_bfloat16* __restrict__ wdTb, __hip_bfloat16* __restrict__ wrTb) {
    int i = blockIdx.x * 256 + threadIdx.x;
    if (i < C_ * KDIM) {
        int k = i % KDIM;          // k = tap*64 + cin
        int co = i / KDIM;
        int tap = k >> 6, cin = k & 63;
        wT1b[i] = __float2bfloat16(w1[(co * C_ + cin) * KTAPS + tap]);
        wToffb[i] = (co < NOFF) ? __float2bfloat16(woff[(co * C_ + cin) * KTAPS + tap])
                                : __float2bfloat16(0.f);
        wdTb[i] = __float2bfloat16(wd[(co * C_ + cin) * KTAPS + tap]);
    }
    if (i < C_ * C_) wrTb[i] = __float2bfloat16(wr[i]);
}

// ---------------------------------------------------------------------------
// x (64, T, H, W) fp32 channel-first -> x_cl (T,H,W,64) bf16 channel-last
// ---------------------------------------------------------------------------
__global__ void to_cl_kernel(const float* __restrict__ x, __hip_bfloat16* __restrict__ xcl) {
    int i = blockIdx.x * 256 + threadIdx.x;   // over 2,097,152
    int pos = i >> 6, ch = i & 63;
    xcl[i] = __float2bfloat16(x[ch * THW_ + pos]);
}

// ---------------------------------------------------------------------------
// MFMA implicit-GEMM 3x3x3 conv, pad=1.
//  in_cl : (T,H,W,64) bf16    wT : (64, 1728) bf16 [cout][tap*64+cin]
//  Block = 256 thr = 4 waves; block covers (t,h) fixed, w=0..63, all 64 couts.
//  Wave wv handles couts [wv*16, wv*16+16); 4 m-subtiles of 16 w-positions.
//  CONV1 epilogue: +bias, lrelu, write channel-last bf16 (LDS bounce).
//  else (offsets conv): +bias, write channel-first fp32, guard cout<NCO.
// ---------------------------------------------------------------------------
template <bool CONV1>
__global__ __launch_bounds__(256) void conv_mfma_kernel(
    const __hip_bfloat16* __restrict__ in_cl,
    const __hip_bfloat16* __restrict__ wT,
    const float* __restrict__ bias,
    __hip_bfloat16* __restrict__ out_cl_b16, // CONV1: (T,H,W,64)
    float* __restrict__ out_cf,              // !CONV1: (NCO,T,H,W)
    int nco) {
    __shared__ float ts[CONV1 ? 64 * 68 : 1];

    const int tid = threadIdx.x;
    const int wv = tid >> 6;
    const int lane = tid & 63;
    const int l15 = lane & 15;
    const int quad = lane >> 4;
    const int t = blockIdx.x >> 6;
    const int h = blockIdx.x & 63;
    const int n0 = wv * 16;
    const int n = n0 + l15;                  // this lane's cout (all regs)

    floatx4 acc[4];
#pragma unroll
    for (int m = 0; m < 4; ++m) acc[m] = (floatx4){0.f, 0.f, 0.f, 0.f};

    const __hip_bfloat16* wB = wT + n * KDIM + quad * 8;   // + tap*64 (+32 for s=1)
    const int wl = l15 - 1;                                 // w offset before +kw

    const bf16x8 zfrag = {};

#pragma unroll 1
    for (int kt = 0; kt < 3; ++kt) {
        const int t_in = t + kt - 1;
        if ((unsigned)t_in >= T_) continue;                 // uniform
#pragma unroll 1
        for (int kh = 0; kh < 3; ++kh) {
            const int h_in = h + kh - 1;
            if ((unsigned)h_in >= H_) continue;             // uniform
            const int rowbase = (t_in * HW_ + h_in * W_);
#pragma unroll
            for (int kw = 0; kw < 3; ++kw) {
                const int tap = kt * 9 + kh * 3 + kw;
                const bf16x8 b0 = *(const bf16x8*)(wB + tap * 64);
                const bf16x8 b1 = *(const bf16x8*)(wB + tap * 64 + 32);
#pragma unroll
                for (int m = 0; m < 4; ++m) {
                    const int w_in = m * 16 + wl + kw;
                    const bool v = (unsigned)w_in < W_;     // per-lane (edge subtiles)
                    const int wc = v ? w_in : 0;
                    const __hip_bfloat16* ap = in_cl + (rowbase + wc) * C_ + quad * 8;
                    bf16x8 a0 = *(const bf16x8*)(ap);
                    bf16x8 a1 = *(const bf16x8*)(ap + 32);
                    a0 = v ? a0 : zfrag;
                    a1 = v ? a1 : zfrag;
                    acc[m] = __builtin_amdgcn_mfma_f32_16x16x32_bf16(a0, b0, acc[m], 0, 0, 0);
                    acc[m] = __builtin_amdgcn_mfma_f32_16x16x32_bf16(a1, b1, acc[m], 0, 0, 0);
                }
            }
        }
    }

    const int posbase = t * HW_ + h * W_;   // linear (t,h,w=0) position

    if constexpr (CONV1) {
        const float bv = bias[n];
#pragma unroll
        for (int m = 0; m < 4; ++m)
#pragma unroll
            for (int r = 0; r < 4; ++r) {
                float v = acc[m][r] + bv;
                v = (v >= 0.f) ? v : 0.01f * v;             // lrelu
                ts[(m * 16 + quad * 4 + r) * 68 + n] = v;   // [w][cout], pad 68
            }
        __syncthreads();
        // cooperative coalesced channel-last bf16 stores
#pragma unroll
        for (int c = 0; c < 4; ++c) {
            const int flat4 = c * 256 + tid;                // 1024 4-float chunks
            const int w = flat4 >> 4, cg = flat4 & 15;
            const float4 v4 = *(const float4*)&ts[w * 68 + cg * 4];
            __hip_bfloat16 hb[4] = {__float2bfloat16(v4.x), __float2bfloat16(v4.y),
                                    __float2bfloat16(v4.z), __float2bfloat16(v4.w)};
            *(uint2*)&out_cl_b16[(posbase + w) * C_ + cg * 4] = *(const uint2*)hb;
        }
    } else {
        const float bv = (n < nco) ? bias[n] : 0.f;
        if (n < nco) {
#pragma unroll
            for (int m = 0; m < 4; ++m) {
                floatx4 v = acc[m];
                v[0] += bv; v[1] += bv; v[2] += bv; v[3] += bv;
                *(floatx4*)&out_cf[n * THW_ + posbase + m * 16 + quad * 4] = v;
            }
        }
    }
}

// ---------------------------------------------------------------------------
// MFMA deformable conv + bias + lrelu + fused 1x1 residual (also MFMA).
//  y1b (T,H,W,64) bf16 cl; off (54,T,H,W) fp32 cf; xclb (T,H,W,64) bf16 cl.
//  wdTb (64,1728) bf16 [cout][tap*64+cin]; wrTb (64,64) bf16 [cout][cin].
//  A-fragments for the deform GEMM are built on the fly: bilinear gather of
//  4 corners from y1b, fp32 blend, pack to bf16. out (64,T,H,W) fp32.
// ---------------------------------------------------------------------------
__global__ __launch_bounds__(256) void deform_mfma_kernel(
    const __hip_bfloat16* __restrict__ y1b, const float* __restrict__ off,
    const __hip_bfloat16* __restrict__ wdTb, const float* __restrict__ bd,
    const __hip_bfloat16* __restrict__ xclb, const __hip_bfloat16* __restrict__ wrTb,
    const float* __restrict__ br, float* __restrict__ out) {
    const int tid = threadIdx.x;
    const int wv = tid >> 6;
    const int lane = tid & 63;
    const int l15 = lane & 15;
    const int quad = lane >> 4;
    const int t = blockIdx.x >> 6;
    const int h = blockIdx.x & 63;
    const int n = wv * 16 + l15;            // this lane's cout
    const int posbase = t * HW_ + h * W_;

    floatx4 acc[4], racc[4];
#pragma unroll
    for (int m = 0; m < 4; ++m) {
        acc[m] = (floatx4){0.f, 0.f, 0.f, 0.f};
        racc[m] = (floatx4){0.f, 0.f, 0.f, 0.f};
    }

    // ---- residual 1x1 conv on x: 8 MFMAs ----
    {
        const __hip_bfloat16* wrB = wrTb + n * C_ + quad * 8;
        const bf16x8 rb0 = *(const bf16x8*)(wrB);
        const bf16x8 rb1 = *(const bf16x8*)(wrB + 32);
#pragma unroll
        for (int m = 0; m < 4; ++m) {
            const __hip_bfloat16* ap = xclb + (posbase + m * 16 + l15) * C_ + quad * 8;
            const bf16x8 a0 = *(const bf16x8*)(ap);
            const bf16x8 a1 = *(const bf16x8*)(ap + 32);
            racc[m] = __builtin_amdgcn_mfma_f32_16x16x32_bf16(a0, rb0, racc[m], 0, 0, 0);
            racc[m] = __builtin_amdgcn_mfma_f32_16x16x32_bf16(a1, rb1, racc[m], 0, 0, 0);
        }
    }

    // ---- deform taps ----
    const __hip_bfloat16* wB = wdTb + n * KDIM + quad * 8;

#pragma unroll 1
    for (int k = 0; k < KTAPS; ++k) {
        const int kt = k / 9, kh = (k / 3) % 3, kw = k % 3;
        const int t_in = t - 1 + kt;
        if ((unsigned)t_in >= T_) continue;                 // block-uniform

        const bf16x8 b0 = *(const bf16x8*)(wB + k * 64);
        const bf16x8 b1 = *(const bf16x8*)(wB + k * 64 + 32);
        const float* offh = off + (2 * k) * THW_ + posbase;
        const float* offw = off + (2 * k + 1) * THW_ + posbase;
        const int tb = t_in * HW_;

#pragma unroll
        for (int m = 0; m < 4; ++m) {
            const int w_ = m * 16 + l15;
            const float dh = offh[w_];
            const float dw = offw[w_];
            const float hs = (float)(h - 1 + kh) + dh;
            const float wsv = (float)(w_ - 1 + kw) + dw;
            const float h0f = floorf(hs), w0f = floorf(wsv);
            const float fh = hs - h0f, fw = wsv - w0f;
            const int h0i = (int)h0f, w0i = (int)w0f;
            const int h1i = h0i + 1, w1i = w0i + 1;
            const float m_h0 = ((unsigned)h0i < H_) ? 1.f : 0.f;
            const float m_h1 = ((unsigned)h1i < H_) ? 1.f : 0.f;
            const float m_w0 = ((unsigned)w0i < W_) ? 1.f : 0.f;
            const float m_w1 = ((unsigned)w1i < W_) ? 1.f : 0.f;
            const float w00 = (1.f - fh) * (1.f - fw) * m_h0 * m_w0;
            const float w01 = (1.f - fh) * fw * m_h0 * m_w1;
            const float w10 = fh * (1.f - fw) * m_h1 * m_w0;
            const float w11 = fh * fw * m_h1 * m_w1;
            const int h0c = min(max(h0i, 0), H_ - 1);
            const int h1c = min(max(h1i, 0), H_ - 1);
            const int w0c = min(max(w0i, 0), W_ - 1);
            const int w1c = min(max(w1i, 0), W_ - 1);

            const __hip_bfloat16* p00 = y1b + (tb + h0c * W_ + w0c) * C_ + quad * 8;
            const __hip_bfloat16* p01 = y1b + (tb + h0c * W_ + w1c) * C_ + quad * 8;
            const __hip_bfloat16* p10 = y1b + (tb + h1c * W_ + w0c) * C_ + quad * 8;
            const __hip_bfloat16* p11 = y1b + (tb + h1c * W_ + w1c) * C_ + quad * 8;

#pragma unroll
            for (int s = 0; s < 2; ++s) {
                union { bf16x8 v; __hip_bfloat16 e[8]; } u00, u01, u10, u11, ua;
                u00.v = *(const bf16x8*)(p00 + s * 32);
                u01.v = *(const bf16x8*)(p01 + s * 32);
                u10.v = *(const bf16x8*)(p10 + s * 32);
                u11.v = *(const bf16x8*)(p11 + s * 32);
#pragma unroll
                for (int j = 0; j < 8; ++j) {
                    float f = w00 * __bfloat162float(u00.e[j]) + w01 * __bfloat162float(u01.e[j]) +
                              w10 * __bfloat162float(u10.e[j]) + w11 * __bfloat162float(u11.e[j]);
                    ua.e[j] = __float2bfloat16(f);
                }
                acc[m] = __builtin_amdgcn_mfma_f32_16x16x32_bf16(ua.v, s ? b1 : b0, acc[m], 0, 0, 0);
            }
        }
    }

    // ---- epilogue: lrelu(deform + bd) + (residual + br) ----
    const float bdv = bd[n];
    const float brv = br[n];
#pragma unroll
    for (int m = 0; m < 4; ++m) {
        floatx4 o;
#pragma unroll
        for (int r = 0; r < 4; ++r) {
            float v = acc[m][r] + bdv;
            v = (v >= 0.f) ? v : 0.01f * v;
            o[r] = v + racc[m][r] + brv;
        }
        *(floatx4*)&out[n * THW_ + posbase + m * 16 + quad * 4] = o;
    }
}

// ---------------------------------------------------------------------------
extern "C" void kernel_launch(void* const* d_in, const int* in_sizes, int n_in,
                              void* d_out, int out_size, void* d_ws, size_t ws_size,
                              hipStream_t stream) {
    const float* x    = (const float*)d_in[0];
    const float* W1   = (const float*)d_in[1];
    const float* b1   = (const float*)d_in[2];
    const float* Woff = (const float*)d_in[3];
    const float* boff = (const float*)d_in[4];
    const float* Wd   = (const float*)d_in[5];
    const float* bd   = (const float*)d_in[6];
    const float* Wr   = (const float*)d_in[7];
    const float* br   = (const float*)d_in[8];
    float* out = (float*)d_out;

    float* ws = (float*)d_ws;
    float* offcf = ws;                                         // 1,769,472 f
    __hip_bfloat16* xclb   = (__hip_bfloat16*)(ws + 1769472);  // 2,097,152 bf16
    __hip_bfloat16* y1b    = (__hip_bfloat16*)(ws + 2818048);  // 2,097,152 bf16
    __hip_bfloat16* wT1b   = (__hip_bfloat16*)(ws + 3866624);  //   110,592 bf16
    __hip_bfloat16* wToffb = (__hip_bfloat16*)(ws + 3921920);  //   110,592 bf16
    __hip_bfloat16* wdTb   = (__hip_bfloat16*)(ws + 3977216);  //   110,592 bf16
    __hip_bfloat16* wrTb   = (__hip_bfloat16*)(ws + 4032512);  //     4,096 bf16
    // total: ~4,034,560 floats ~= 16.1 MB

    prep_kernel<<<(C_ * KDIM + 255) / 256, 256, 0, stream>>>(
        W1, Woff, Wd, Wr, wT1b, wToffb, wdTb, wrTb);

    to_cl_kernel<<<(C_ * THW_) / 256, 256, 0, stream>>>(x, xclb);

    // y1 = lrelu(conv(x, W1, b1)) -> channel-last bf16
    conv_mfma_kernel<true><<<dim3(T_ * H_), 256, 0, stream>>>(
        xclb, wT1b, b1, y1b, nullptr, 64);

    // offsets = conv(y1, W_off, b_off) -> channel-first fp32 (54 ch)
    conv_mfma_kernel<false><<<dim3(T_ * H_), 256, 0, stream>>>(
        y1b, wToffb, boff, nullptr, offcf, NOFF);

    // y2 = lrelu(deform(y1, offsets, Wd, bd)) + (Wr·x + br)
    deform_mfma_kernel<<<dim3(T_ * H_), 256, 0, stream>>>(
        y1b, offcf, wdTb, bd, xclb, wrTb, br, out);
}